// Round 1
// baseline (642.889 us; speedup 1.0000x reference)
//
#include <hip/hip_runtime.h>

// ---------------------------------------------------------------------------
// entropy_57346403336670:
//   C = normalize_rows(ex) @ normalize_rows(ey)^T   (16384 x 16384, K=256)
//   e1 = -sum(exp(lp(rowmax))*lp(rowmax)), e2 = same over colmax
//   lp(v) = -(v-1)^2/(2*0.3^2) - (log(0.3)+0.5*log(2*pi))
// Strategy: f32 normalize -> f16, MFMA f16 GEMM (128^2 tile, BK=32) with
// fused row/col max epilogue via monotone-uint atomicMax. No C materialized.
// ---------------------------------------------------------------------------

typedef _Float16 f16x8 __attribute__((ext_vector_type(8)));
typedef _Float16 f16x4 __attribute__((ext_vector_type(4)));
typedef float f32x4 __attribute__((ext_vector_type(4)));

#define N_ROWS 16384
#define KDIM 256

__device__ inline void gl_lds16(const void* g, void* l) {
  __builtin_amdgcn_global_load_lds(
      (const __attribute__((address_space(1))) void*)g,
      (__attribute__((address_space(3))) void*)l, 16, 0, 0);
}

// monotone float->uint transform (order-preserving for all reals)
__device__ inline unsigned f2mono(float f) {
  unsigned b = __float_as_uint(f);
  return (b & 0x80000000u) ? ~b : (b | 0x80000000u);
}
__device__ inline float mono2f(unsigned u) {
  return __uint_as_float((u & 0x80000000u) ? (u ^ 0x80000000u) : ~u);
}

// --------------------------- normalize + cast ------------------------------
// one wave per row; 64 lanes x float4 = 256 cols
__global__ __launch_bounds__(256) void normalize_k(
    const float* __restrict__ ex, const float* __restrict__ ey,
    _Float16* __restrict__ xn, _Float16* __restrict__ yn) {
  const int lane = threadIdx.x & 63;
  const int row = blockIdx.x * 4 + (threadIdx.x >> 6);
  const float* src;
  _Float16* dst;
  if (row < N_ROWS) {
    src = ex + (size_t)row * KDIM;
    dst = xn + (size_t)row * KDIM;
  } else {
    src = ey + (size_t)(row - N_ROWS) * KDIM;
    dst = yn + (size_t)(row - N_ROWS) * KDIM;
  }
  float4 v = *reinterpret_cast<const float4*>(src + lane * 4);
  float ss = v.x * v.x + v.y * v.y + v.z * v.z + v.w * v.w;
#pragma unroll
  for (int m = 1; m <= 32; m <<= 1) ss += __shfl_xor(ss, m, 64);
  float inv = 1.0f / fmaxf(sqrtf(ss), 1e-8f);
  f16x4 o;
  o[0] = (_Float16)(v.x * inv);
  o[1] = (_Float16)(v.y * inv);
  o[2] = (_Float16)(v.z * inv);
  o[3] = (_Float16)(v.w * inv);
  *reinterpret_cast<f16x4*>(dst + lane * 4) = o;
}

// ------------------------------ GEMM + max ---------------------------------
// 128x128 tile, BK=32 (one mfma_16x16x32 K-step), 4 waves in 2x2, 64x64/wave.
// LDS tile rows are 64B; k-group XOR swizzle (g' = g ^ (row&3)) spreads the
// 16-lane row-column read across 8 bank-groups (2-way = free). Since
// global_load_lds writes linearly, the swizzle is applied to the GLOBAL
// source column (involution) and to the ds_read address (rule #21).
__global__ __launch_bounds__(256) void gemm_max_k(
    const _Float16* __restrict__ X, const _Float16* __restrict__ Y,
    unsigned* __restrict__ rmax, unsigned* __restrict__ cmax) {
  __shared__ __align__(16) _Float16 As[2][128 * 32];
  __shared__ __align__(16) _Float16 Bs[2][128 * 32];

  const int tid = threadIdx.x;
  const int lane = tid & 63;
  const int wid = tid >> 6;
  const int wr = wid >> 1;
  const int wc = wid & 1;

  // XCD-aware swizzle: 16384 blocks, 8 XCDs, bijective since 16384 % 8 == 0
  const int nwg = gridDim.x;
  const int bid = blockIdx.x;
  const int wg = (bid & 7) * (nwg >> 3) + (bid >> 3);
  const int tm = wg >> 7;   // tile row (X panel), 128 consecutive wg share tm
  const int tn = wg & 127;  // tile col (Y panel)

  // staging: thread t stages 16B at linear LDS byte t*16 (and +4096).
  // linear byte o -> row r = o/64, k-group g' = (o/16)&3; source col is the
  // inverse swizzle (g' ^ (r&3))*8 halves. r and r+64 share r&3.
  const int r0 = tid >> 2;
  const int c0 = ((tid & 3) ^ (r0 & 3)) * 8;
  const _Float16* xa = X + (size_t)(tm * 128 + r0) * KDIM + c0;
  const _Float16* xb = xa + (size_t)64 * KDIM;
  const _Float16* ya = Y + (size_t)(tn * 128 + r0) * KDIM + c0;
  const _Float16* yb = ya + (size_t)64 * KDIM;
  char* lAs = (char*)&As[0][0];
  char* lBs = (char*)&Bs[0][0];

  // fragment read offsets: row = base + (lane&15), swizzled k-group
  const int fr = lane & 15;
  const int fg = (lane >> 4) ^ (lane & 3);  // row&3 == lane&3
  int aoff[4], boff[4];
#pragma unroll
  for (int m = 0; m < 4; ++m) aoff[m] = (wr * 64 + m * 16 + fr) * 64 + fg * 16;
#pragma unroll
  for (int n = 0; n < 4; ++n) boff[n] = (wc * 64 + n * 16 + fr) * 64 + fg * 16;

  f32x4 acc[4][4] = {};

  // prologue: stage K-tile 0 into buffer 0
  gl_lds16(xa, lAs + tid * 16);
  gl_lds16(xb, lAs + 4096 + tid * 16);
  gl_lds16(ya, lBs + tid * 16);
  gl_lds16(yb, lBs + 4096 + tid * 16);
  __syncthreads();  // drains vmcnt(0) -> buf0 ready

#pragma unroll
  for (int kt = 0; kt < 8; ++kt) {
    const int b = kt & 1;
    if (kt < 7) {  // prefetch next K-tile into the other buffer
      const int ko = (kt + 1) * 32;
      const int bo = (b ^ 1) * 8192;
      gl_lds16(xa + ko, lAs + bo + tid * 16);
      gl_lds16(xb + ko, lAs + bo + 4096 + tid * 16);
      gl_lds16(ya + ko, lBs + bo + tid * 16);
      gl_lds16(yb + ko, lBs + bo + 4096 + tid * 16);
    }
    const int bo = b * 8192;
    f16x8 af[4], bfv[4];
#pragma unroll
    for (int m = 0; m < 4; ++m)
      af[m] = *reinterpret_cast<const f16x8*>(lAs + bo + aoff[m]);
#pragma unroll
    for (int n = 0; n < 4; ++n)
      bfv[n] = *reinterpret_cast<const f16x8*>(lBs + bo + boff[n]);
#pragma unroll
    for (int m = 0; m < 4; ++m)
#pragma unroll
      for (int n = 0; n < 4; ++n)
        acc[m][n] =
            __builtin_amdgcn_mfma_f32_16x16x32_f16(af[m], bfv[n], acc[m][n], 0, 0, 0);
    __syncthreads();  // drains prefetch vmcnt + protects buffer reuse
  }

  // ---- epilogue: fused row/col max ----
  // C/D layout (m89-verified): col = lane&15, row = (lane>>4)*4 + reg
  // row max: reduce over n frags + the 16 lanes sharing (lane>>4)
#pragma unroll
  for (int m = 0; m < 4; ++m) {
#pragma unroll
    for (int r = 0; r < 4; ++r) {
      float v = fmaxf(fmaxf(acc[m][0][r], acc[m][1][r]),
                      fmaxf(acc[m][2][r], acc[m][3][r]));
#pragma unroll
      for (int msk = 1; msk <= 8; msk <<= 1) v = fmaxf(v, __shfl_xor(v, msk, 64));
      if ((lane & 15) == 0) {
        const int row = tm * 128 + wr * 64 + m * 16 + (lane >> 4) * 4 + r;
        atomicMax(&rmax[row], f2mono(v));
      }
    }
  }
  // col max: reduce over m,reg in-register, then across the 4 subgroups
#pragma unroll
  for (int n = 0; n < 4; ++n) {
    float v = -1e30f;
#pragma unroll
    for (int m = 0; m < 4; ++m)
#pragma unroll
      for (int r = 0; r < 4; ++r) v = fmaxf(v, acc[m][n][r]);
    v = fmaxf(v, __shfl_xor(v, 16, 64));
    v = fmaxf(v, __shfl_xor(v, 32, 64));
    if (lane < 16) {
      const int col = tn * 128 + wc * 64 + n * 16 + lane;
      atomicMax(&cmax[col], f2mono(v));
    }
  }
}

// ------------------------------ finalize -----------------------------------
// blockIdx 0 -> e1 (rowmax), blockIdx 1 -> e2 (colmax)
__global__ __launch_bounds__(256) void finalize_k(
    const unsigned* __restrict__ rmax, const unsigned* __restrict__ cmax,
    float* __restrict__ out) {
  const unsigned* src = (blockIdx.x == 0) ? rmax : cmax;
  float sum = 0.0f;
  for (int i = threadIdx.x; i < N_ROWS; i += 256) {
    float v = mono2f(src[i]);
    float d = v - 1.0f;
    // lp = -d^2/(2*0.3^2) - (log(0.3)+0.5*log(2pi)) = -d^2*5.5556 + 0.28503427
    float lp = fmaf(-d * d, 5.5555555556f, 0.2850342717f);
    sum += expf(lp) * lp;
  }
#pragma unroll
  for (int m = 1; m <= 32; m <<= 1) sum += __shfl_xor(sum, m, 64);
  __shared__ float partial[4];
  if ((threadIdx.x & 63) == 0) partial[threadIdx.x >> 6] = sum;
  __syncthreads();
  if (threadIdx.x == 0)
    out[blockIdx.x] = -(partial[0] + partial[1] + partial[2] + partial[3]);
}

// ---------------------------------------------------------------------------
extern "C" void kernel_launch(void* const* d_in, const int* in_sizes, int n_in,
                              void* d_out, int out_size, void* d_ws, size_t ws_size,
                              hipStream_t stream) {
  const float* ex = (const float*)d_in[0];
  const float* ey = (const float*)d_in[1];
  char* wsb = (char*)d_ws;
  // ws layout: xn f16 8MB | yn f16 8MB | rmax 64KB | cmax 64KB  (16.2 MB)
  _Float16* xn = (_Float16*)wsb;
  _Float16* yn = (_Float16*)(wsb + 8388608);
  unsigned* rmax = (unsigned*)(wsb + 16777216);
  unsigned* cmax = (unsigned*)(wsb + 16777216 + 65536);

  hipMemsetAsync(wsb + 16777216, 0, 131072, stream);  // rmax+cmax := 0 (== -NaN mono floor)
  normalize_k<<<8192, 256, 0, stream>>>(ex, ey, xn, yn);
  gemm_max_k<<<16384, 256, 0, stream>>>(xn, yn, rmax, cmax);
  finalize_k<<<2, 256, 0, stream>>>(rmax, cmax, (float*)d_out);
}

// Round 2
// 442.040 us; speedup vs baseline: 1.4544x; 1.4544x over previous
//
#include <hip/hip_runtime.h>

// ---------------------------------------------------------------------------
// entropy_57346403336670:
//   C = normalize_rows(ex) @ normalize_rows(ey)^T   (16384 x 16384, K=256)
//   e1 = -sum(exp(lp(rowmax))*lp(rowmax)), e2 = same over colmax
// R2: 256x256 tile, BK=32 dbuf (64 KB LDS), 8 waves (2x4), 32x32x16 f16 MFMA,
//     conflict-free 3-bit XOR LDS swizzle, block-level LDS max-reduction
//     before global atomics. No C materialized.
// ---------------------------------------------------------------------------

typedef _Float16 f16x8 __attribute__((ext_vector_type(8)));
typedef _Float16 f16x4 __attribute__((ext_vector_type(4)));
typedef float f32x16 __attribute__((ext_vector_type(16)));

#define NROWS 16384
#define KDIM 256

__device__ inline void gl_lds16(const void* g, void* l) {
  __builtin_amdgcn_global_load_lds(
      (const __attribute__((address_space(1))) void*)g,
      (__attribute__((address_space(3))) void*)l, 16, 0, 0);
}

// monotone float->uint transform (order-preserving)
__device__ inline unsigned f2mono(float f) {
  unsigned b = __float_as_uint(f);
  return (b & 0x80000000u) ? ~b : (b | 0x80000000u);
}
__device__ inline float mono2f(unsigned u) {
  return __uint_as_float((u & 0x80000000u) ? (u ^ 0x80000000u) : ~u);
}

// --------------------------- normalize + cast ------------------------------
__global__ __launch_bounds__(256) void normalize_k(
    const float* __restrict__ ex, const float* __restrict__ ey,
    _Float16* __restrict__ xn, _Float16* __restrict__ yn) {
  const int lane = threadIdx.x & 63;
  const int row = blockIdx.x * 4 + (threadIdx.x >> 6);
  const float* src;
  _Float16* dst;
  if (row < NROWS) {
    src = ex + (size_t)row * KDIM;
    dst = xn + (size_t)row * KDIM;
  } else {
    src = ey + (size_t)(row - NROWS) * KDIM;
    dst = yn + (size_t)(row - NROWS) * KDIM;
  }
  float4 v = *reinterpret_cast<const float4*>(src + lane * 4);
  float ss = v.x * v.x + v.y * v.y + v.z * v.z + v.w * v.w;
#pragma unroll
  for (int m = 1; m <= 32; m <<= 1) ss += __shfl_xor(ss, m, 64);
  float inv = 1.0f / fmaxf(sqrtf(ss), 1e-8f);
  f16x4 o;
  o[0] = (_Float16)(v.x * inv);
  o[1] = (_Float16)(v.y * inv);
  o[2] = (_Float16)(v.z * inv);
  o[3] = (_Float16)(v.w * inv);
  *reinterpret_cast<f16x4*>(dst + lane * 4) = o;
}

// ------------------------------ GEMM + max ---------------------------------
// LDS tile row = 32 halves = 64 B = 4 x 16B groups. bank-slot(16B granule) =
// (row&1)*4 + g. Swizzle g' = g ^ ((row>>1)&3): a wave b128 read (64 lanes,
// rows base+lane&31, group kk*2+(lane>>5)) hits all 8 slots x 8 lanes = HW
// minimum -> conflict-free. global_load_lds writes linearly, so the inverse
// swizzle is applied to the GLOBAL source column (involution, rule #21).
__global__ __launch_bounds__(512) void gemm_max_k(
    const _Float16* __restrict__ X, const _Float16* __restrict__ Y,
    unsigned* __restrict__ rmax, unsigned* __restrict__ cmax) {
  __shared__ __align__(16) _Float16 As[2][256 * 32];
  __shared__ __align__(16) _Float16 Bs[2][256 * 32];

  const int tid = threadIdx.x;
  const int lane = tid & 63;
  const int wid = tid >> 6;  // 0..7
  const int wr = wid >> 2;   // 0..1  (wave covers rows wr*128..+127)
  const int wc = wid & 3;    // 0..3  (cols wc*64..+63)

  // XCD swizzle: 4096 blocks, 4096 % 8 == 0 -> bijective
  const int bid = blockIdx.x;
  const int wg = (bid & 7) * 512 + (bid >> 3);
  const int tm = wg >> 6;  // 0..63
  const int tn = wg & 63;  // 0..63

  // ---- staging addresses (thread t stages 16B chunks c=t and c=t+512) ----
  // chunk c: LDS byte c*16 -> row=c>>2, g=c&3; source group = g ^ ((row>>1)&3)
  const int srow = tid >> 2;  // 0..127 (round 0); round 1 adds 128 (same swz)
  const int sg = (tid & 3) ^ ((srow >> 1) & 3);
  const _Float16* xa = X + (size_t)(tm * 256 + srow) * KDIM + sg * 8;
  const _Float16* xb = xa + (size_t)128 * KDIM;
  const _Float16* ya = Y + (size_t)(tn * 256 + srow) * KDIM + sg * 8;
  const _Float16* yb = ya + (size_t)128 * KDIM;
  char* lA = (char*)&As[0][0];
  char* lB = (char*)&Bs[0][0];
  const int d0 = tid * 16, d1 = tid * 16 + 8192;

  // ---- fragment read offsets (kk=0; kk=1 is ^32) ----
  // A frag (32x32x16): row = lane&31, k = (lane>>5)*8 + i
  const int h = lane >> 5;
  int aoff[4], boff[2];
#pragma unroll
  for (int m = 0; m < 4; ++m) {
    int row = wr * 128 + m * 32 + (lane & 31);
    aoff[m] = row * 64 + (h ^ ((row >> 1) & 3)) * 16;
  }
#pragma unroll
  for (int n = 0; n < 2; ++n) {
    int row = wc * 64 + n * 32 + (lane & 31);
    boff[n] = row * 64 + (h ^ ((row >> 1) & 3)) * 16;
  }

  f32x16 acc[4][2] = {};

  // prologue: stage K-tile 0 into buffer 0
  gl_lds16(xa, lA + d0);
  gl_lds16(xb, lA + d1);
  gl_lds16(ya, lB + d0);
  gl_lds16(yb, lB + d1);
  __syncthreads();

#pragma unroll
  for (int kt = 0; kt < 8; ++kt) {
    const int b = kt & 1;
    if (kt < 7) {  // prefetch next K-tile into the other buffer
      const int ko = (kt + 1) * 32;
      const int bo2 = (b ^ 1) * 16384;
      gl_lds16(xa + ko, lA + bo2 + d0);
      gl_lds16(xb + ko, lA + bo2 + d1);
      gl_lds16(ya + ko, lB + bo2 + d0);
      gl_lds16(yb + ko, lB + bo2 + d1);
    }
    const int bo = b * 16384;
    f16x8 af[4], bf[2];
    // kk = 0
#pragma unroll
    for (int m = 0; m < 4; ++m) af[m] = *(const f16x8*)(lA + bo + aoff[m]);
#pragma unroll
    for (int n = 0; n < 2; ++n) bf[n] = *(const f16x8*)(lB + bo + boff[n]);
#pragma unroll
    for (int m = 0; m < 4; ++m)
#pragma unroll
      for (int n = 0; n < 2; ++n)
        acc[m][n] = __builtin_amdgcn_mfma_f32_32x32x16_f16(af[m], bf[n],
                                                           acc[m][n], 0, 0, 0);
    // kk = 1 (byte offset ^32 flips the k-group pair under the swizzle)
#pragma unroll
    for (int m = 0; m < 4; ++m) af[m] = *(const f16x8*)(lA + bo + (aoff[m] ^ 32));
#pragma unroll
    for (int n = 0; n < 2; ++n) bf[n] = *(const f16x8*)(lB + bo + (boff[n] ^ 32));
#pragma unroll
    for (int m = 0; m < 4; ++m)
#pragma unroll
      for (int n = 0; n < 2; ++n)
        acc[m][n] = __builtin_amdgcn_mfma_f32_32x32x16_f16(af[m], bf[n],
                                                           acc[m][n], 0, 0, 0);
    __syncthreads();
  }

  // ---- epilogue: block-level max reduction in (reused) LDS ----
  // C/D 32x32 layout: col = lane&31, row = (reg&3) + 8*(reg>>2) + 4*(lane>>5)
  unsigned* rs = (unsigned*)lA;        // [256] row maxes (local)
  unsigned* cs = rs + 256;             // [256] col maxes (local)
  rs[tid] = 0;                         // tid 0..511 covers both arrays
  __syncthreads();

  // rows: reduce the 32 cols of each (m,reg,h) value across lanes-of-half
#pragma unroll
  for (int m = 0; m < 4; ++m) {
#pragma unroll
    for (int r = 0; r < 16; ++r) {
      float v = fmaxf(acc[m][0][r], acc[m][1][r]);
#pragma unroll
      for (int msk = 1; msk <= 16; msk <<= 1) v = fmaxf(v, __shfl_xor(v, msk, 64));
      if ((lane & 31) == 0) {
        const int row = wr * 128 + m * 32 + (r & 3) + 8 * (r >> 2) + 4 * h;
        atomicMax(&rs[row], f2mono(v));
      }
    }
  }
  // cols: per lane reduce over m,reg; combine the two halves (same cols)
#pragma unroll
  for (int n = 0; n < 2; ++n) {
    float v = -1e30f;
#pragma unroll
    for (int m = 0; m < 4; ++m)
#pragma unroll
      for (int r = 0; r < 16; ++r) v = fmaxf(v, acc[m][n][r]);
    v = fmaxf(v, __shfl_xor(v, 32, 64));
    if (lane < 32) atomicMax(&cs[wc * 64 + n * 32 + lane], f2mono(v));
  }
  __syncthreads();

  // one dense wave-instruction batch of global atomics per block
  if (tid < 256)
    atomicMax(&rmax[tm * 256 + tid], rs[tid]);
  else
    atomicMax(&cmax[tn * 256 + (tid - 256)], cs[tid - 256]);
}

// ------------------------------ finalize -----------------------------------
__global__ __launch_bounds__(256) void finalize_k(
    const unsigned* __restrict__ rmax, const unsigned* __restrict__ cmax,
    float* __restrict__ out) {
  const unsigned* src = (blockIdx.x == 0) ? rmax : cmax;
  float sum = 0.0f;
  for (int i = threadIdx.x; i < NROWS; i += 256) {
    float v = mono2f(src[i]);
    float d = v - 1.0f;
    // lp = -d^2/(2*0.3^2) - (log(0.3)+0.5*log(2pi))
    float lp = fmaf(-d * d, 5.5555555556f, 0.2850342717f);
    sum += expf(lp) * lp;
  }
#pragma unroll
  for (int m = 1; m <= 32; m <<= 1) sum += __shfl_xor(sum, m, 64);
  __shared__ float partial[4];
  if ((threadIdx.x & 63) == 0) partial[threadIdx.x >> 6] = sum;
  __syncthreads();
  if (threadIdx.x == 0)
    out[blockIdx.x] = -(partial[0] + partial[1] + partial[2] + partial[3]);
}

// ---------------------------------------------------------------------------
extern "C" void kernel_launch(void* const* d_in, const int* in_sizes, int n_in,
                              void* d_out, int out_size, void* d_ws, size_t ws_size,
                              hipStream_t stream) {
  const float* ex = (const float*)d_in[0];
  const float* ey = (const float*)d_in[1];
  char* wsb = (char*)d_ws;
  // ws layout: xn f16 8MB | yn f16 8MB | rmax 64KB | cmax 64KB
  _Float16* xn = (_Float16*)wsb;
  _Float16* yn = (_Float16*)(wsb + 8388608);
  unsigned* rmax = (unsigned*)(wsb + 16777216);
  unsigned* cmax = (unsigned*)(wsb + 16777216 + 65536);

  hipMemsetAsync(wsb + 16777216, 0, 131072, stream);  // mono-floor = 0
  normalize_k<<<8192, 256, 0, stream>>>(ex, ey, xn, yn);
  gemm_max_k<<<4096, 512, 0, stream>>>(xn, yn, rmax, cmax);
  finalize_k<<<2, 256, 0, stream>>>(rmax, cmax, (float*)d_out);
}

// Round 3
// 436.395 us; speedup vs baseline: 1.4732x; 1.0129x over previous
//
#include <hip/hip_runtime.h>

// ---------------------------------------------------------------------------
// entropy_57346403336670:
//   C = normalize_rows(ex) @ normalize_rows(ey)^T   (16384 x 16384, K=256)
//   e1 = -sum(exp(lp(rowmax))*lp(rowmax)), e2 = same over colmax
// R3: persistent blocks. 256 blocks (1/CU), each owns a 4x4 supertile of
//     256x256 tiles. Flattened 64-step pipeline (16 tiles x 4 K-steps of
//     BK=64): one barrier per step, stage issued one full step ahead so the
//     barrier's vmcnt drain is ~free. 8 waves (2x4), wave-tile 128x64,
//     mfma_f32_32x32x16_f16. 3-bit LDS slot swizzle (row stride 128 B).
//     Fused row/col max epilogue per tile. No C materialized.
// ---------------------------------------------------------------------------

typedef _Float16 f16x8 __attribute__((ext_vector_type(8)));
typedef _Float16 f16x4 __attribute__((ext_vector_type(4)));
typedef float f32x16 __attribute__((ext_vector_type(16)));

#define NROWS 16384
#define KDIM 256

__device__ inline void gl_lds16(const void* g, void* l) {
  __builtin_amdgcn_global_load_lds(
      (const __attribute__((address_space(1))) void*)g,
      (__attribute__((address_space(3))) void*)l, 16, 0, 0);
}

// monotone float->uint transform (order-preserving)
__device__ inline unsigned f2mono(float f) {
  unsigned b = __float_as_uint(f);
  return (b & 0x80000000u) ? ~b : (b | 0x80000000u);
}
__device__ inline float mono2f(unsigned u) {
  return __uint_as_float((u & 0x80000000u) ? (u ^ 0x80000000u) : ~u);
}

// --------------------------- normalize + cast ------------------------------
__global__ __launch_bounds__(256) void normalize_k(
    const float* __restrict__ ex, const float* __restrict__ ey,
    _Float16* __restrict__ xn, _Float16* __restrict__ yn) {
  const int lane = threadIdx.x & 63;
  const int row = blockIdx.x * 4 + (threadIdx.x >> 6);
  const float* src;
  _Float16* dst;
  if (row < NROWS) {
    src = ex + (size_t)row * KDIM;
    dst = xn + (size_t)row * KDIM;
  } else {
    src = ey + (size_t)(row - NROWS) * KDIM;
    dst = yn + (size_t)(row - NROWS) * KDIM;
  }
  float4 v = *reinterpret_cast<const float4*>(src + lane * 4);
  float ss = v.x * v.x + v.y * v.y + v.z * v.z + v.w * v.w;
#pragma unroll
  for (int m = 1; m <= 32; m <<= 1) ss += __shfl_xor(ss, m, 64);
  float inv = 1.0f / fmaxf(sqrtf(ss), 1e-8f);
  f16x4 o;
  o[0] = (_Float16)(v.x * inv);
  o[1] = (_Float16)(v.y * inv);
  o[2] = (_Float16)(v.z * inv);
  o[3] = (_Float16)(v.w * inv);
  *reinterpret_cast<f16x4*>(dst + lane * 4) = o;
}

// ------------------------------ GEMM + max ---------------------------------
// LDS per parity half (64 KB x 2): A tile 256x64 f16 (32 KB) | B tile (32 KB).
// Row = 128 B = one full bank line -> unswizzled col-reads are 32-way
// conflicts. Swizzle the 16B slot: slot' = slot ^ (row & 7). Wave b128 reads
// (rows = base + lane&31) then cover all 8 slots in every 8-lane group ->
// conflict-free. global_load_lds writes LDS linearly, so the inverse (same
// XOR) is applied to the GLOBAL source column (rule #21).
__global__ __launch_bounds__(512, 2) void gemm_max_k(
    const _Float16* __restrict__ X, const _Float16* __restrict__ Y,
    unsigned* __restrict__ rmax, unsigned* __restrict__ cmax) {
  __shared__ __align__(16) char smem[133120];  // 2*64KB buffers + 2KB reduce

  const int tid = threadIdx.x;
  const int lane = tid & 63;
  const int wid = tid >> 6;  // 0..7
  const int wr = wid >> 2;   // 0..1 : rows wr*128..+127
  const int wc = wid & 3;    // 0..3 : cols wc*64..+63
  const int h = lane >> 5;   // half-wave

  // block -> 4x4 supertile; XCD x owns a compact 2-super-row band
  const int bid = blockIdx.x;
  const int lid = bid >> 3;
  const int sm4 = ((bid & 7) * 2 + (lid >> 4)) * 4;  // tile-row base (0..60)
  const int sn4 = (lid & 15) * 4;                    // tile-col base (0..60)

  // ---- staging precompute: thread t stages 8 chunks of 16 B per step ----
  // A chunk c = tid + 512q: LDS byte c*16 -> row = c>>3, slot = c&7.
  // source slot = (c&7) ^ (row&7); row&7 == (tid>>3)&7 for all q.
  const int srow0 = tid >> 3;                        // 0..63
  const int scol = ((tid & 7) ^ (srow0 & 7)) << 3;   // halves
  const _Float16* xs = X + (size_t)srow0 * KDIM + scol;
  const _Float16* ys = Y + (size_t)srow0 * KDIM + scol;
  char* ldsA = smem + tid * 16;
  char* ldsB = smem + 32768 + tid * 16;

  // ---- fragment read offsets ----
  // A row = wr*128 + m*32 + (lane&31); k-halves [kk*16 + h*8, +8)
  // slot = kk*2 + h, swizzled ^ (row&7) == ^ (lane&7)
  int sl[4];
#pragma unroll
  for (int kk = 0; kk < 4; ++kk) sl[kk] = ((((kk << 1) | h) ^ (lane & 7)) << 4);
  int abase[4], bbase[2];
#pragma unroll
  for (int m = 0; m < 4; ++m) abase[m] = (wr * 128 + m * 32 + (lane & 31)) * 128;
#pragma unroll
  for (int n = 0; n < 2; ++n)
    bbase[n] = 32768 + (wc * 64 + n * 32 + (lane & 31)) * 128;

  unsigned* rs = (unsigned*)(smem + 131072);  // [256] row maxes
  unsigned* cs = rs + 256;                    // [256] col maxes
  rs[tid] = 0;                                // tid 0..511 covers both

  const f32x16 vzero = {};
  f32x16 acc[4][2] = {};

  // ---- prologue: stage step 0 (tile 0 -> tm=sm4, tn=sn4, kq=0, par=0) ----
#pragma unroll
  for (int q = 0; q < 4; ++q) {
    gl_lds16(xs + ((size_t)sm4 * 65536 + q * 16384), ldsA + q * 8192);
    gl_lds16(ys + ((size_t)sn4 * 65536 + q * 16384), ldsB + q * 8192);
  }

  for (int t = 0; t < 16; ++t) {
    const int tm = sm4 + (t & 3);
    const int tn = sn4 + (t >> 2);
#pragma unroll
    for (int kq = 0; kq < 4; ++kq) {
      // top barrier: waits stage[s] (issued one full step ago -> cheap) and
      // guarantees all waves finished reading the buffer we stage into next.
      __syncthreads();
      const int u = t * 4 + kq + 1;  // next step
      if (u < 64) {
        const int tu = u >> 2;
        const int tmu = sm4 + (tu & 3);
        const int tnu = sn4 + (tu >> 2);
        const int kqu = u & 3;
        const int pu = (u & 1) * 65536;
#pragma unroll
        for (int q = 0; q < 4; ++q) {
          gl_lds16(xs + ((size_t)tmu * 65536 + q * 16384 + kqu * 64),
                   ldsA + pu + q * 8192);
          gl_lds16(ys + ((size_t)tnu * 65536 + q * 16384 + kqu * 64),
                   ldsB + pu + q * 8192);
        }
      }
      const int po = (kq & 1) * 65536;
      __builtin_amdgcn_s_setprio(1);
#pragma unroll
      for (int kk = 0; kk < 4; ++kk) {
        f16x8 a0 = *(const f16x8*)(smem + po + abase[0] + sl[kk]);
        f16x8 a1 = *(const f16x8*)(smem + po + abase[1] + sl[kk]);
        f16x8 a2 = *(const f16x8*)(smem + po + abase[2] + sl[kk]);
        f16x8 a3 = *(const f16x8*)(smem + po + abase[3] + sl[kk]);
        f16x8 b0 = *(const f16x8*)(smem + po + bbase[0] + sl[kk]);
        f16x8 b1 = *(const f16x8*)(smem + po + bbase[1] + sl[kk]);
        acc[0][0] = __builtin_amdgcn_mfma_f32_32x32x16_f16(a0, b0, acc[0][0], 0, 0, 0);
        acc[0][1] = __builtin_amdgcn_mfma_f32_32x32x16_f16(a0, b1, acc[0][1], 0, 0, 0);
        acc[1][0] = __builtin_amdgcn_mfma_f32_32x32x16_f16(a1, b0, acc[1][0], 0, 0, 0);
        acc[1][1] = __builtin_amdgcn_mfma_f32_32x32x16_f16(a1, b1, acc[1][1], 0, 0, 0);
        acc[2][0] = __builtin_amdgcn_mfma_f32_32x32x16_f16(a2, b0, acc[2][0], 0, 0, 0);
        acc[2][1] = __builtin_amdgcn_mfma_f32_32x32x16_f16(a2, b1, acc[2][1], 0, 0, 0);
        acc[3][0] = __builtin_amdgcn_mfma_f32_32x32x16_f16(a3, b0, acc[3][0], 0, 0, 0);
        acc[3][1] = __builtin_amdgcn_mfma_f32_32x32x16_f16(a3, b1, acc[3][1], 0, 0, 0);
      }
      __builtin_amdgcn_s_setprio(0);
    }

    // ---- per-tile epilogue (overlaps the in-flight next-tile stage) ----
    // C/D 32x32 layout: col = lane&31, row = (r&3) + 8*(r>>2) + 4*h
#pragma unroll
    for (int m = 0; m < 4; ++m) {
#pragma unroll
      for (int r = 0; r < 16; ++r) {
        float v = fmaxf(acc[m][0][r], acc[m][1][r]);
#pragma unroll
        for (int msk = 1; msk <= 16; msk <<= 1)
          v = fmaxf(v, __shfl_xor(v, msk, 64));
        if ((lane & 31) == 0)
          atomicMax(&rs[wr * 128 + m * 32 + (r & 3) + 8 * (r >> 2) + 4 * h],
                    f2mono(v));
      }
    }
#pragma unroll
    for (int n = 0; n < 2; ++n) {
      float v = -1e30f;
#pragma unroll
      for (int m = 0; m < 4; ++m)
#pragma unroll
        for (int r = 0; r < 16; ++r) v = fmaxf(v, acc[m][n][r]);
      v = fmaxf(v, __shfl_xor(v, 32, 64));
      if (lane < 32) atomicMax(&cs[wc * 64 + n * 32 + lane], f2mono(v));
    }
    __syncthreads();  // all ds-atomics into rs/cs done
    if (tid < 256) {
      atomicMax(&rmax[tm * 256 + tid], rs[tid]);
      rs[tid] = 0;
    } else {
      atomicMax(&cmax[tn * 256 + (tid - 256)], cs[tid - 256]);
      cs[tid - 256] = 0;
    }
#pragma unroll
    for (int m = 0; m < 4; ++m)
#pragma unroll
      for (int n = 0; n < 2; ++n) acc[m][n] = vzero;
    // resets are ordered before the next tile's ds-atomics by the K-step
    // barriers in between.
  }
}

// ------------------------------ finalize -----------------------------------
__global__ __launch_bounds__(256) void finalize_k(
    const unsigned* __restrict__ rmax, const unsigned* __restrict__ cmax,
    float* __restrict__ out) {
  const unsigned* src = (blockIdx.x == 0) ? rmax : cmax;
  float sum = 0.0f;
  for (int i = threadIdx.x; i < NROWS; i += 256) {
    float v = mono2f(src[i]);
    float d = v - 1.0f;
    // lp = -d^2/(2*0.3^2) - (log(0.3)+0.5*log(2pi))
    float lp = fmaf(-d * d, 5.5555555556f, 0.2850342717f);
    sum += expf(lp) * lp;
  }
#pragma unroll
  for (int m = 1; m <= 32; m <<= 1) sum += __shfl_xor(sum, m, 64);
  __shared__ float partial[4];
  if ((threadIdx.x & 63) == 0) partial[threadIdx.x >> 6] = sum;
  __syncthreads();
  if (threadIdx.x == 0)
    out[blockIdx.x] = -(partial[0] + partial[1] + partial[2] + partial[3]);
}

// ---------------------------------------------------------------------------
extern "C" void kernel_launch(void* const* d_in, const int* in_sizes, int n_in,
                              void* d_out, int out_size, void* d_ws, size_t ws_size,
                              hipStream_t stream) {
  const float* ex = (const float*)d_in[0];
  const float* ey = (const float*)d_in[1];
  char* wsb = (char*)d_ws;
  // ws layout: xn f16 8MB | yn f16 8MB | rmax 64KB | cmax 64KB
  _Float16* xn = (_Float16*)wsb;
  _Float16* yn = (_Float16*)(wsb + 8388608);
  unsigned* rmax = (unsigned*)(wsb + 16777216);
  unsigned* cmax = (unsigned*)(wsb + 16777216 + 65536);

  hipMemsetAsync(wsb + 16777216, 0, 131072, stream);  // mono-floor = 0
  normalize_k<<<8192, 256, 0, stream>>>(ex, ey, xn, yn);
  gemm_max_k<<<256, 512, 0, stream>>>(xn, yn, rmax, cmax);
  finalize_k<<<2, 256, 0, stream>>>(rmax, cmax, (float*)d_out);
}